// Round 1
// baseline (462.306 us; speedup 1.0000x reference)
//
#include <hip/hip_runtime.h>
#include <hip/hip_bf16.h>

// Problem constants (from reference)
constexpr int       DIM       = 128;
constexpr long long CN        = 131073;               // 1 + QUEUE_K
constexpr long long OUT_ELEMS = 256LL * 131073LL;     // 33554688
constexpr long long PROBS_OFF = OUT_ELEMS;
constexpr long long MEMOUT_OFF = OUT_ELEMS + 1;
constexpr long long MEM_ELEMS = 131072LL * 128LL;     // 16777216

constexpr float SCL = 20.60992915555662f;             // log2(e)/0.07  (exp(x/T) = 2^(x*SCL))

// ws layout (float indices)
constexpr int WS_INVZ  = 0;
constexpr int WS_ELPOS = 16;     // 256 floats
constexpr int WS_KMEAN = 272;    // 64*128 floats
constexpr int WS_ROWP  = 8464;   // 32 slices x 256 floats
constexpr int WS_QB    = 16656;  // q as bf16 (ushort[32768] = 64KB), 16B aligned

typedef __attribute__((ext_vector_type(8))) short  short8v;
typedef __attribute__((ext_vector_type(4))) float  f32x4;

__device__ __forceinline__ unsigned short f2bf(float x) {
  unsigned u = __float_as_uint(x);
  u += 0x7fffu + ((u >> 16) & 1u);   // round-to-nearest-even
  return (unsigned short)(u >> 16);
}

__global__ void k_init(float* __restrict__ ws) {
  int i = blockIdx.x * 256 + threadIdx.x;
  if (i < 32 * 256) ws[WS_ROWP + i] = 0.f;
}

__global__ void k_prep(const float* __restrict__ q, const float* __restrict__ k,
                       float* __restrict__ ws) {
  int b = blockIdx.x, t = threadIdx.x;
  if (b < 128) {                       // q -> bf16
    int i = b * 256 + t;
    unsigned short* qb = (unsigned short*)(ws + WS_QB);
    qb[i] = f2bf(q[i]);
  } else if (b < 160) {                // k_mean per video (indices = v, v+64, v+128, v+192)
    int j = (b - 128) * 256 + t;
    int v = j >> 7, d = j & 127;
    ws[WS_KMEAN + j] = 0.25f * (k[v*128+d] + k[(v+64)*128+d] +
                                k[(v+128)*128+d] + k[(v+192)*128+d]);
  } else {                             // exp(l_pos/T), one thread per row
    int row = t, vid = t & 63;
    float acc = 0.f;
    for (int d = 0; d < DIM; ++d) {
      float s = 0.f;
      #pragma unroll
      for (int c = 0; c < 4; ++c) {
        int rr = vid + c * 64;
        if (rr != row) s += k[rr*128 + d];
      }
      acc += q[row*128 + d] * s;
    }
    ws[WS_ELPOS + row] = exp2f(acc * (1.f/3.f) * SCL);
  }
}

// PASS 0: accumulate row sums of exp into ws (no out writes).
// PASS 1: write exp * invZ to out[:, 1:].
template<int PASS>
__global__ __launch_bounds__(256) void k_gemm(const float* __restrict__ memv,
                                              float* __restrict__ ws,
                                              float* __restrict__ out) {
  __shared__ __align__(16) char lds[8192];   // 32 rows x 128 bf16 (256B rows), XOR-swizzled
  const int t = threadIdx.x;
  const int n0 = blockIdx.x * 32;
  float invZ = 1.f;
  if (PASS == 1) invZ = ws[WS_INVZ];

  // stage mem tile (rows n0..n0+31) as bf16 into LDS
  {
    const float4* src = (const float4*)(memv + (long long)n0 * DIM);
    #pragma unroll
    for (int j = 0; j < 4; ++j) {
      int fi4 = t + j * 256;
      float4 v = src[fi4];
      int fi = fi4 * 4;
      int n = fi >> 7;
      int byteoff = (fi * 2) ^ ((n & 7) << 4);
      ushort4 h;
      h.x = f2bf(v.x); h.y = f2bf(v.y); h.z = f2bf(v.z); h.w = f2bf(v.w);
      *(ushort4*)(lds + byteoff) = h;
    }
  }
  __syncthreads();

  const int lane = t & 63, wave = t >> 6;
  const int g = lane >> 4, nlo = lane & 15;
  f32x4 zero = {0.f, 0.f, 0.f, 0.f};
  f32x4 acc[4][2];
  #pragma unroll
  for (int mf = 0; mf < 4; ++mf) { acc[mf][0] = zero; acc[mf][1] = zero; }

  const char* qb = (const char*)(ws + WS_QB);
  #pragma unroll
  for (int ks = 0; ks < 4; ++ks) {
    short8v bfr[2];
    #pragma unroll
    for (int nf = 0; nf < 2; ++nf) {
      int n = nf * 16 + nlo;
      int byteoff = (n * 256 + ks * 64 + g * 16) ^ ((n & 7) << 4);
      bfr[nf] = *(const short8v*)(lds + byteoff);
    }
    #pragma unroll
    for (int mf = 0; mf < 4; ++mf) {
      int m = wave * 64 + mf * 16 + nlo;
      short8v af = *(const short8v*)(qb + (m * 128 + ks * 32 + g * 8) * 2);
      acc[mf][0] = __builtin_amdgcn_mfma_f32_16x16x32_bf16(af, bfr[0], acc[mf][0], 0, 0, 0);
      acc[mf][1] = __builtin_amdgcn_mfma_f32_16x16x32_bf16(af, bfr[1], acc[mf][1], 0, 0, 0);
    }
  }

  float* rowp = ws + WS_ROWP + (blockIdx.x & 31) * 256;
  #pragma unroll
  for (int mf = 0; mf < 4; ++mf) {
    #pragma unroll
    for (int r = 0; r < 4; ++r) {
      int row = wave * 64 + mf * 16 + g * 4 + r;   // D: col=lane&15, row=4*(lane>>4)+reg
      float v0 = exp2f(acc[mf][0][r] * SCL);
      float v1 = exp2f(acc[mf][1][r] * SCL);
      if (PASS == 0) {
        float part = v0 + v1;
        part += __shfl_xor(part, 1, 16);
        part += __shfl_xor(part, 2, 16);
        part += __shfl_xor(part, 4, 16);
        part += __shfl_xor(part, 8, 16);
        if (nlo == 0) atomicAdd(&rowp[row], part);
      } else {
        long long base = (long long)row * CN + 1 + n0;
        out[base + nlo]      = v0 * invZ;
        out[base + 16 + nlo] = v1 * invZ;
      }
    }
  }
}

__global__ void k_fin(float* __restrict__ ws, float* __restrict__ out) {
  __shared__ float s_tot[256];
  __shared__ float s_pr[256];
  __shared__ float sh_invZ;
  int t = threadIdx.x;
  float s = ws[WS_ELPOS + t];
  float rs = s;                         // row sum includes column 0
  for (int sl = 0; sl < 32; ++sl) rs += ws[WS_ROWP + sl * 256 + t];
  s_tot[t] = rs;
  s_pr[t] = s / rs;                     // scale-invariant ratio
  __syncthreads();
  for (int off = 128; off > 0; off >>= 1) {
    if (t < off) { s_tot[t] += s_tot[t + off]; s_pr[t] += s_pr[t + off]; }
    __syncthreads();
  }
  if (t == 0) {
    double Z = (double)s_tot[0] * (1000000.0 / (256.0 * 131073.0));
    float invZ = (float)(1.0 / Z);
    ws[WS_INVZ] = invZ;
    sh_invZ = invZ;
    out[PROBS_OFF] = s_pr[0] * (1.f / 256.f);
  }
  __syncthreads();
  out[(long long)t * CN] = s * sh_invZ; // out[:,0] scaled
}

__global__ void k_copy(const float* __restrict__ memv, const float* __restrict__ ws,
                       float* __restrict__ out) {
  float* dst = out + MEMOUT_OFF;        // NOTE: 4B-aligned only (offset is odd)
  const float* km = ws + WS_KMEAN;
  long long gid = blockIdx.x * 256LL + threadIdx.x;
  if (gid == 0) {                       // head (0..2) + tail element, scalar
    dst[0] = km[0]; dst[1] = km[1]; dst[2] = km[2];
    dst[MEM_ELEMS - 1] = memv[MEM_ELEMS - 1];
  }
  const long long ng = (MEM_ELEMS - 4) / 4;  // groups of 4 starting at element 3 (16B-aligned dst)
  long long stride = (long long)gridDim.x * 256LL;
  for (long long i = gid; i < ng; i += stride) {
    long long base = 3 + i * 4;
    float4 v;
    if (base + 4 <= 8192) {
      v.x = km[base]; v.y = km[base+1]; v.z = km[base+2]; v.w = km[base+3];
    } else if (base >= 8192) {
      v.x = memv[base]; v.y = memv[base+1]; v.z = memv[base+2]; v.w = memv[base+3];
    } else {
      float tmp[4];
      #pragma unroll
      for (int e = 0; e < 4; ++e) {
        long long idx = base + e;
        tmp[e] = (idx < 8192) ? km[idx] : memv[idx];
      }
      v.x = tmp[0]; v.y = tmp[1]; v.z = tmp[2]; v.w = tmp[3];
    }
    *(float4*)(dst + base) = v;
  }
}

extern "C" void kernel_launch(void* const* d_in, const int* in_sizes, int n_in,
                              void* d_out, int out_size, void* d_ws, size_t ws_size,
                              hipStream_t stream) {
  (void)in_sizes; (void)n_in; (void)out_size; (void)ws_size;
  const float* q    = (const float*)d_in[0];
  const float* k    = (const float*)d_in[1];
  const float* memv = (const float*)d_in[2];
  float* out = (float*)d_out;
  float* ws  = (float*)d_ws;

  hipLaunchKernelGGL(k_init, dim3(32),   dim3(256), 0, stream, ws);
  hipLaunchKernelGGL(k_prep, dim3(161),  dim3(256), 0, stream, q, k, ws);
  hipLaunchKernelGGL((k_gemm<0>), dim3(4096), dim3(256), 0, stream, memv, ws, out);
  hipLaunchKernelGGL(k_fin,  dim3(1),    dim3(256), 0, stream, ws, out);
  hipLaunchKernelGGL((k_gemm<1>), dim3(4096), dim3(256), 0, stream, memv, ws, out);
  hipLaunchKernelGGL(k_copy, dim3(2048), dim3(256), 0, stream, memv, ws, out);
}

// Round 2
// 399.811 us; speedup vs baseline: 1.1563x; 1.1563x over previous
//
#include <hip/hip_runtime.h>
#include <hip/hip_bf16.h>

// Problem constants
constexpr int       DIM        = 128;
constexpr long long CN         = 131073;               // 1 + QUEUE_K
constexpr long long OUT_ELEMS  = 256LL * 131073LL;     // 33554688
constexpr long long PROBS_OFF  = OUT_ELEMS;
constexpr long long MEMOUT_OFF = OUT_ELEMS + 1;
constexpr long long MEM_ELEMS  = 131072LL * 128LL;     // 16777216

constexpr float SCL = 20.60992915555662f;              // log2(e)/0.07

// ws layout (float indices)
constexpr int WS_INVZ  = 0;
constexpr int WS_ELPOS = 16;      // 256 floats
constexpr int WS_KMEAN = 272;     // 64*128 floats
constexpr int WS_ROWP  = 8464;    // 32 slices x 256 floats
constexpr int WS_QB    = 16656;   // q as bf16: ushort[32768] (64KB), 16B aligned
constexpr int WS_MEMBF = 33040;   // memory as bf16: ushort[16777216] (32MB), 16B aligned

// k_prep job ranges (block index)
constexpr int PB_Q    = 8192;   // [0,8192): memv->bf16 (8 elems/thread)
constexpr int PB_KM   = 8208;   // [8192,8208): q->bf16
constexpr int PB_LPOS = 8240;   // [8208,8240): k_mean
constexpr int PB_ZERO = 8304;   // [8240,8304): l_pos (1 wave/row)
constexpr int PREP_BLOCKS = 8308; // [8304,8308): zero rowp

typedef __attribute__((ext_vector_type(8))) short  short8v;
typedef __attribute__((ext_vector_type(4))) float  f32x4;

__device__ __forceinline__ unsigned short f2bf(float x) {
  unsigned u = __float_as_uint(x);
  u += 0x7fffu + ((u >> 16) & 1u);   // RNE
  return (unsigned short)(u >> 16);
}

__device__ __forceinline__ short8v pack8(float4 a, float4 b) {
  short8v h;
  h[0] = (short)f2bf(a.x); h[1] = (short)f2bf(a.y);
  h[2] = (short)f2bf(a.z); h[3] = (short)f2bf(a.w);
  h[4] = (short)f2bf(b.x); h[5] = (short)f2bf(b.y);
  h[6] = (short)f2bf(b.z); h[7] = (short)f2bf(b.w);
  return h;
}

__global__ __launch_bounds__(256) void k_prep(const float* __restrict__ q,
                                              const float* __restrict__ k,
                                              const float* __restrict__ memv,
                                              float* __restrict__ ws) {
  const int b = blockIdx.x, t = threadIdx.x;
  if (b < PB_Q) {                      // memory -> bf16, 8 f32/thread
    long long gid = (long long)b * 256 + t;
    const float4* src = (const float4*)memv;
    float4 a = src[2 * gid], c = src[2 * gid + 1];
    short8v* dst = (short8v*)((unsigned short*)(ws + WS_MEMBF) + gid * 8);
    *dst = pack8(a, c);
  } else if (b < PB_KM) {              // q -> bf16
    int gid = (b - PB_Q) * 256 + t;
    const float4* src = (const float4*)q;
    float4 a = src[2 * gid], c = src[2 * gid + 1];
    short8v* dst = (short8v*)((unsigned short*)(ws + WS_QB) + gid * 8);
    *dst = pack8(a, c);
  } else if (b < PB_LPOS) {            // k_mean per video
    int j = (b - PB_KM) * 256 + t;
    int v = j >> 7, d = j & 127;
    ws[WS_KMEAN + j] = 0.25f * (k[v*128+d] + k[(v+64)*128+d] +
                                k[(v+128)*128+d] + k[(v+192)*128+d]);
  } else if (b < PB_ZERO) {            // exp(l_pos/T): one wave per row
    int row = (b - PB_LPOS) * 4 + (t >> 6);
    int lane = t & 63;
    int vid = row & 63;
    float2 qv = ((const float2*)(q + row * DIM))[lane];
    float2 kr = ((const float2*)(k + row * DIM))[lane];
    float s0 = -kr.x, s1 = -kr.y;
    #pragma unroll
    for (int c = 0; c < 4; ++c) {
      float2 kc = ((const float2*)(k + (vid + c * 64) * DIM))[lane];
      s0 += kc.x; s1 += kc.y;
    }
    float acc = qv.x * s0 + qv.y * s1;
    #pragma unroll
    for (int off = 1; off < 64; off <<= 1) acc += __shfl_xor(acc, off, 64);
    if (lane == 0) ws[WS_ELPOS + row] = exp2f(acc * (1.f / 3.f) * SCL);
  } else {                             // zero rowp (32*256 floats)
    int i = (b - PB_ZERO) * 2048 + t * 8;
    float4 z = {0.f, 0.f, 0.f, 0.f};
    *(float4*)(ws + WS_ROWP + i)     = z;
    *(float4*)(ws + WS_ROWP + i + 4) = z;
  }
}

// PASS 0: accumulate row sums of exp (atomics into rowp). PASS 1: write out[:,1:].
// No LDS: B fragments loaded straight from bf16 memory copy; af (q frags) register-resident.
template<int PASS, int NT, int GRID>
__global__ __launch_bounds__(256) void k_gemm(const unsigned short* __restrict__ membf,
                                              const unsigned short* __restrict__ qb,
                                              float* __restrict__ ws,
                                              float* __restrict__ out) {
  const int t = threadIdx.x, lane = t & 63, wave = t >> 6;
  const int g = lane >> 4, nlo = lane & 15;
  float invZ = 0.f;
  if (PASS == 1) invZ = ws[WS_INVZ];

  short8v af[4][4];                            // [ks][mf]
  #pragma unroll
  for (int ks = 0; ks < 4; ++ks)
    #pragma unroll
    for (int mf = 0; mf < 4; ++mf)
      af[ks][mf] = *(const short8v*)(qb + (wave*64 + mf*16 + nlo) * DIM + ks*32 + g*8);

  float sums[4][4];
  if (PASS == 0) {
    #pragma unroll
    for (int mf = 0; mf < 4; ++mf)
      #pragma unroll
      for (int r = 0; r < 4; ++r) sums[mf][r] = 0.f;
  }

  for (int it = 0; it < NT; ++it) {
    const int tile = blockIdx.x + it * GRID;
    const long long n0 = (long long)tile * 32;
    f32x4 acc[4][2];
    f32x4 zero = {0.f, 0.f, 0.f, 0.f};
    #pragma unroll
    for (int mf = 0; mf < 4; ++mf) { acc[mf][0] = zero; acc[mf][1] = zero; }

    #pragma unroll
    for (int ks = 0; ks < 4; ++ks) {
      short8v b0 = *(const short8v*)(membf + (n0 + nlo)      * DIM + ks*32 + g*8);
      short8v b1 = *(const short8v*)(membf + (n0 + 16 + nlo) * DIM + ks*32 + g*8);
      #pragma unroll
      for (int mf = 0; mf < 4; ++mf) {
        acc[mf][0] = __builtin_amdgcn_mfma_f32_16x16x32_bf16(af[ks][mf], b0, acc[mf][0], 0, 0, 0);
        acc[mf][1] = __builtin_amdgcn_mfma_f32_16x16x32_bf16(af[ks][mf], b1, acc[mf][1], 0, 0, 0);
      }
    }

    #pragma unroll
    for (int mf = 0; mf < 4; ++mf) {
      #pragma unroll
      for (int r = 0; r < 4; ++r) {
        float v0 = exp2f(acc[mf][0][r] * SCL);
        float v1 = exp2f(acc[mf][1][r] * SCL);
        if (PASS == 0) {
          sums[mf][r] += v0 + v1;
        } else {
          int row = wave*64 + mf*16 + g*4 + r;   // D: col=lane&15, row=4*(lane>>4)+reg
          long long base = (long long)row * CN + 1 + n0;
          out[base + nlo]      = v0 * invZ;
          out[base + 16 + nlo] = v1 * invZ;
        }
      }
    }
  }

  if (PASS == 0) {
    float* rowp = ws + WS_ROWP + (blockIdx.x & 31) * 256;
    #pragma unroll
    for (int mf = 0; mf < 4; ++mf) {
      #pragma unroll
      for (int r = 0; r < 4; ++r) {
        float s = sums[mf][r];
        s += __shfl_xor(s, 1, 16);
        s += __shfl_xor(s, 2, 16);
        s += __shfl_xor(s, 4, 16);
        s += __shfl_xor(s, 8, 16);
        if (nlo == 0) atomicAdd(&rowp[wave*64 + mf*16 + g*4 + r], s);
      }
    }
  }
}

__global__ void k_fin(float* __restrict__ ws, float* __restrict__ out) {
  __shared__ float s_tot[256];
  __shared__ float s_pr[256];
  __shared__ float sh_invZ;
  int t = threadIdx.x;
  float s = ws[WS_ELPOS + t];
  float rs = s;
  for (int sl = 0; sl < 32; ++sl) rs += ws[WS_ROWP + sl * 256 + t];
  s_tot[t] = rs;
  s_pr[t] = s / rs;                     // scale-invariant
  __syncthreads();
  for (int off = 128; off > 0; off >>= 1) {
    if (t < off) { s_tot[t] += s_tot[t + off]; s_pr[t] += s_pr[t + off]; }
    __syncthreads();
  }
  if (t == 0) {
    double Z = (double)s_tot[0] * (1000000.0 / (256.0 * 131073.0));
    float invZ = (float)(1.0 / Z);
    ws[WS_INVZ] = invZ;
    sh_invZ = invZ;
    out[PROBS_OFF] = s_pr[0] * (1.f / 256.f);
  }
  __syncthreads();
  out[(long long)t * CN] = s * sh_invZ;
}

__global__ void k_copy(const float* __restrict__ memv, const float* __restrict__ ws,
                       float* __restrict__ out) {
  float* dst = out + MEMOUT_OFF;        // 4B-aligned only (offset is odd)
  const float* km = ws + WS_KMEAN;
  long long gid = blockIdx.x * 256LL + threadIdx.x;
  if (gid == 0) {
    dst[0] = km[0]; dst[1] = km[1]; dst[2] = km[2];
    dst[MEM_ELEMS - 1] = memv[MEM_ELEMS - 1];
  }
  const long long ng = (MEM_ELEMS - 4) / 4;  // float4 groups from element 3 (16B-aligned dst)
  long long stride = (long long)gridDim.x * 256LL;
  for (long long i = gid; i < ng; i += stride) {
    long long base = 3 + i * 4;
    float4 v;
    if (base + 4 <= 8192) {
      v.x = km[base]; v.y = km[base+1]; v.z = km[base+2]; v.w = km[base+3];
    } else if (base >= 8192) {
      v.x = memv[base]; v.y = memv[base+1]; v.z = memv[base+2]; v.w = memv[base+3];
    } else {
      float tmp[4];
      #pragma unroll
      for (int e = 0; e < 4; ++e) {
        long long idx = base + e;
        tmp[e] = (idx < 8192) ? km[idx] : memv[idx];
      }
      v.x = tmp[0]; v.y = tmp[1]; v.z = tmp[2]; v.w = tmp[3];
    }
    *(float4*)(dst + base) = v;
  }
}

extern "C" void kernel_launch(void* const* d_in, const int* in_sizes, int n_in,
                              void* d_out, int out_size, void* d_ws, size_t ws_size,
                              hipStream_t stream) {
  (void)in_sizes; (void)n_in; (void)out_size; (void)ws_size;
  const float* q    = (const float*)d_in[0];
  const float* k    = (const float*)d_in[1];
  const float* memv = (const float*)d_in[2];
  float* out = (float*)d_out;
  float* ws  = (float*)d_ws;
  const unsigned short* membf = (const unsigned short*)(ws + WS_MEMBF);
  const unsigned short* qb    = (const unsigned short*)(ws + WS_QB);

  hipLaunchKernelGGL(k_prep, dim3(PREP_BLOCKS), dim3(256), 0, stream, q, k, memv, ws);
  hipLaunchKernelGGL((k_gemm<0, 8, 512>),  dim3(512),  dim3(256), 0, stream, membf, qb, ws, out);
  hipLaunchKernelGGL(k_fin,  dim3(1),    dim3(256), 0, stream, ws, out);
  hipLaunchKernelGGL((k_gemm<1, 4, 1024>), dim3(1024), dim3(256), 0, stream, membf, qb, ws, out);
  hipLaunchKernelGGL(k_copy, dim3(2048), dim3(256), 0, stream, memv, ws, out);
}